// Round 10
// baseline (3189.865 us; speedup 1.0000x reference)
//
#include <hip/hip_runtime.h>
#include <cstdint>
#include <cstddef>

#define B_ 4
#define T_ 24
#define N_ 512

// gate nonlinearities: evaluate in f64, round once to f32 (R4-proven numerics)
__device__ __forceinline__ float fsig(float x)  { return (float)(1.0 / (1.0 + exp(-(double)x))); }
__device__ __forceinline__ float ftanh(float x) { return (float)tanh((double)x); }

// 16-slot XOR swizzle for [F][64] LDS tiles (R7-proven)
__device__ __forceinline__ int swz16(int f) { return (((f & 15) ^ ((f >> 4) & 15)) << 2); }

// ================= PRECOMPUTE (parallel, recurrence-free) =================

// xp = relu(x @ fc_w + fc_b), stored feature-major xpT[bt][f][node]
__global__ __launch_bounds__(256) void xpT_kernel(const float* __restrict__ x,
                                                  const float* __restrict__ fc_w,
                                                  const float* __restrict__ fc_b,
                                                  float* __restrict__ xpT) {
    __shared__ __align__(16) float sX[64 * 68];
    __shared__ __align__(16) float sW[64 * 64];
    __shared__ float sB[64];
    const int bt = blockIdx.y;
    const int n0 = blockIdx.x * 64;
    const int tid = threadIdx.x;
    for (int i = tid * 4; i < 4096; i += 1024)
        *(float4*)&sW[i] = *(const float4*)&fc_w[i];
    if (tid < 64) sB[tid] = fc_b[tid];
    {
        int r = tid >> 2, kq = (tid & 3) * 16;
        const float* p = x + ((size_t)bt * N_ + n0 + r) * 64 + kq;
        #pragma unroll
        for (int j = 0; j < 4; ++j)
            *(float4*)&sX[r * 68 + kq + j * 4] = *(const float4*)(p + j * 4);
    }
    __syncthreads();
    const int f = tid & 63, ng = tid >> 6;
    float d[16];
    #pragma unroll
    for (int j = 0; j < 16; ++j) d[j] = 0.f;
    for (int k = 0; k < 64; ++k) {
        float w = sW[k * 64 + f];
        #pragma unroll
        for (int j = 0; j < 16; ++j)
            d[j] = fmaf(sX[(ng * 16 + j) * 68 + k], w, d[j]);
    }
    const float bias = sB[f];
    float* o = xpT + ((size_t)bt * 64 + f) * N_ + n0 + ng * 16;
    #pragma unroll
    for (int j = 0; j < 16; ++j)
        o[j] = fmaxf(__fadd_rn(d[j], bias), 0.f);
}

// UX[bt][node][64] = (A_bt @ xp_bt): 1 wave per block, RPT=8, A via uniform (scalar) loads
__global__ __launch_bounds__(64) void ux_kernel(const float* __restrict__ e,
                                                const float* __restrict__ xpT,
                                                float* __restrict__ UX) {
    __shared__ __align__(16) float sV[2][64 * 64];   // 32 KB dbuf
    const int bt = blockIdx.y;
    const int m0 = blockIdx.x * 8;
    const int lane = threadIdx.x;
    const float* Ab = e + ((size_t)bt * N_ + m0) * N_;
    const float* s0 = xpT + (size_t)bt * 64 * N_;
    auto stageV = [&](float* dst, int kt) {
        #pragma unroll
        for (int j = 0; j < 16; ++j) {
            int id = j * 64 + lane;
            int f = id >> 4, kq = (id & 15) * 4;
            *(float4*)&dst[f * 64 + (kq ^ swz16(f))] =
                *(const float4*)&s0[(size_t)f * N_ + kt * 64 + kq];
        }
    };
    stageV(sV[0], 0);
    __syncthreads();
    const int swc = swz16(lane);
    float acc[8];
    #pragma unroll
    for (int r = 0; r < 8; ++r) acc[r] = 0.f;
    for (int kb = 0; kb < 8; ++kb) {
        if (kb < 7) stageV(sV[(kb + 1) & 1], kb + 1);
        const float* buf = sV[kb & 1];
        #pragma unroll 4
        for (int kg = 0; kg < 16; ++kg) {
            float4 v = *(const float4*)&buf[lane * 64 + ((kg * 4) ^ swc)];
            #pragma unroll
            for (int r = 0; r < 8; ++r) {
                const float* Ar = Ab + (size_t)r * N_ + kb * 64 + kg * 4;  // wave-uniform
                acc[r] = fmaf(Ar[0], v.x, acc[r]);
                acc[r] = fmaf(Ar[1], v.y, acc[r]);
                acc[r] = fmaf(Ar[2], v.z, acc[r]);
                acc[r] = fmaf(Ar[3], v.w, acc[r]);
            }
        }
        __syncthreads();
    }
    #pragma unroll
    for (int r = 0; r < 8; ++r)
        UX[((size_t)bt * N_ + m0 + r) * 64 + lane] = acc[r];
}

// ================= STAGE KERNELS (multi-launch, BM=8, 256 blocks, 128 thr) =================
// S1: C = A@h;        hz = relu([UX|C]@Wz1); hr = relu([UX|C]@Wr1)
// S2: C = A@[hz|hr];  z = sig(C_z@Wz2) -> zT; rh = sig(C_r@Wr2)*h
// S3: C = A@rh;       hc = relu(UX@Wc1_top + C@Wc1_bot)
// S4: C = A@hc;       c = tanh(C@Wc2); hn = z*h + (1-z)*c -> hT, out
template <int STAGE>
__global__ __launch_bounds__(128) void stage_kernel(
    const float* __restrict__ e, int t, const float* __restrict__ UX,
    const float* __restrict__ Wz1, const float* __restrict__ Wz2,
    const float* __restrict__ Wr1, const float* __restrict__ Wr2,
    const float* __restrict__ Wc1, const float* __restrict__ Wc2,
    float* __restrict__ hT, float* __restrict__ hzT, float* __restrict__ hrT,
    float* __restrict__ zT, float* __restrict__ rhT, float* __restrict__ hcT,
    float* __restrict__ out)
{
    constexpr int F  = (STAGE == 2) ? 128 : 64;
    constexpr int SC = F + 4;
    __shared__ __align__(16) float sV[2][F * 64];   // 32 KB (F=64) / 64 KB (F=128)
    __shared__ __align__(16) float sC[8 * SC];
    __shared__ __align__(16) float sUX[8 * 68];

    const int b = blockIdx.y, m0 = blockIdx.x * 8;
    const int tid = threadIdx.x, lane = tid & 63, w = tid >> 6;
    const int bt = b * T_ + t;
    const float* Ab = e + ((size_t)bt * N_ + m0) * N_;

    const float* s0;
    const float* s1 = nullptr;
    if (STAGE == 1)      { s0 = hT  + (size_t)b * 64 * N_; }
    else if (STAGE == 2) { s0 = hzT + (size_t)b * 64 * N_; s1 = hrT + (size_t)b * 64 * N_; }
    else if (STAGE == 3) { s0 = rhT + (size_t)b * 64 * N_; }
    else                 { s0 = hcT + (size_t)b * 64 * N_; }

    if constexpr (STAGE == 1 || STAGE == 3) {
        int n = tid >> 4, q = (tid & 15) * 4;
        *(float4*)&sUX[n * 68 + q] =
            *(const float4*)&UX[((size_t)bt * N_ + m0 + n) * 64 + q];
    }

    auto stageV = [&](float* dst, int kt) {
        #pragma unroll
        for (int j = 0; j < F / 8; ++j) {
            int id = j * 128 + tid;
            int f = id >> 4, kq = (id & 15) * 4;
            const float* src = (F == 64 || f < 64) ? (s0 + (size_t)f * N_)
                                                   : (s1 + (size_t)(f - 64) * N_);
            *(float4*)&dst[f * 64 + (kq ^ swz16(f))] =
                *(const float4*)&src[kt * 64 + kq];
        }
    };

    // ---- conv: C = A @ V. A via wave-uniform scalar loads; strict ascending-k chains ----
    constexpr int RPT = (F == 128) ? 8 : 4;
    const int c  = (F == 128) ? tid : lane;
    const int r0 = (F == 128) ? 0 : w * 4;
    const int swc = swz16(c);
    float acc[RPT];
    #pragma unroll
    for (int i = 0; i < RPT; ++i) acc[i] = 0.f;

    stageV(sV[0], 0);
    __syncthreads();
    for (int kb = 0; kb < 8; ++kb) {
        if (kb < 7) stageV(sV[(kb + 1) & 1], kb + 1);
        const float* buf = sV[kb & 1];
        #pragma unroll 4
        for (int kg = 0; kg < 16; ++kg) {
            float4 v = *(const float4*)&buf[c * 64 + ((kg * 4) ^ swc)];
            #pragma unroll
            for (int i = 0; i < RPT; ++i) {
                const float* Ar = Ab + (size_t)(r0 + i) * N_ + kb * 64 + kg * 4;  // uniform
                acc[i] = fmaf(Ar[0], v.x, acc[i]);
                acc[i] = fmaf(Ar[1], v.y, acc[i]);
                acc[i] = fmaf(Ar[2], v.z, acc[i]);
                acc[i] = fmaf(Ar[3], v.w, acc[i]);
            }
        }
        __syncthreads();
    }
    #pragma unroll
    for (int i = 0; i < RPT; ++i)
        sC[(r0 + i) * SC + c] = acc[i];
    __syncthreads();

    // ---- epilogues: lane=f, wave=row-half; W loads reused across 4 rows (+2 gates) ----
    const int f = lane, n0 = w * 4;

    if constexpr (STAGE == 1) {
        float dz[4] = {0.f, 0.f, 0.f, 0.f}, dr[4] = {0.f, 0.f, 0.f, 0.f};
        #pragma unroll 4
        for (int k = 0; k < 64; ++k) {
            float wz = Wz1[k * 64 + f], wr = Wr1[k * 64 + f];
            #pragma unroll
            for (int i = 0; i < 4; ++i) {
                float u = sUX[(n0 + i) * 68 + k];
                dz[i] = fmaf(u, wz, dz[i]);
                dr[i] = fmaf(u, wr, dr[i]);
            }
        }
        #pragma unroll 4
        for (int k = 0; k < 64; ++k) {
            float wz = Wz1[(64 + k) * 64 + f], wr = Wr1[(64 + k) * 64 + f];
            #pragma unroll
            for (int i = 0; i < 4; ++i) {
                float cv = sC[(n0 + i) * SC + k];
                dz[i] = fmaf(cv, wz, dz[i]);
                dr[i] = fmaf(cv, wr, dr[i]);
            }
        }
        *(float4*)(hzT + ((size_t)b * 64 + f) * N_ + m0 + n0) =
            make_float4(fmaxf(dz[0], 0.f), fmaxf(dz[1], 0.f), fmaxf(dz[2], 0.f), fmaxf(dz[3], 0.f));
        *(float4*)(hrT + ((size_t)b * 64 + f) * N_ + m0 + n0) =
            make_float4(fmaxf(dr[0], 0.f), fmaxf(dr[1], 0.f), fmaxf(dr[2], 0.f), fmaxf(dr[3], 0.f));
    }

    if constexpr (STAGE == 2) {
        float dz[4] = {0.f, 0.f, 0.f, 0.f}, dr[4] = {0.f, 0.f, 0.f, 0.f};
        #pragma unroll 4
        for (int k = 0; k < 64; ++k) {
            float wz = Wz2[k * 64 + f], wr = Wr2[k * 64 + f];
            #pragma unroll
            for (int i = 0; i < 4; ++i) {
                float cz = sC[(n0 + i) * SC + k];
                float cr = sC[(n0 + i) * SC + 64 + k];
                dz[i] = fmaf(cz, wz, dz[i]);
                dr[i] = fmaf(cr, wr, dr[i]);
            }
        }
        float4 h4 = *(const float4*)(hT + ((size_t)b * 64 + f) * N_ + m0 + n0);
        *(float4*)(zT + ((size_t)b * 64 + f) * N_ + m0 + n0) =
            make_float4(fsig(dz[0]), fsig(dz[1]), fsig(dz[2]), fsig(dz[3]));
        *(float4*)(rhT + ((size_t)b * 64 + f) * N_ + m0 + n0) =
            make_float4(__fmul_rn(fsig(dr[0]), h4.x), __fmul_rn(fsig(dr[1]), h4.y),
                        __fmul_rn(fsig(dr[2]), h4.z), __fmul_rn(fsig(dr[3]), h4.w));
    }

    if constexpr (STAGE == 3) {
        float d[4] = {0.f, 0.f, 0.f, 0.f};
        #pragma unroll 4
        for (int k = 0; k < 64; ++k) {
            float wc = Wc1[k * 64 + f];
            #pragma unroll
            for (int i = 0; i < 4; ++i)
                d[i] = fmaf(sUX[(n0 + i) * 68 + k], wc, d[i]);
        }
        #pragma unroll 4
        for (int k = 0; k < 64; ++k) {
            float wc = Wc1[(64 + k) * 64 + f];
            #pragma unroll
            for (int i = 0; i < 4; ++i)
                d[i] = fmaf(sC[(n0 + i) * SC + k], wc, d[i]);
        }
        *(float4*)(hcT + ((size_t)b * 64 + f) * N_ + m0 + n0) =
            make_float4(fmaxf(d[0], 0.f), fmaxf(d[1], 0.f), fmaxf(d[2], 0.f), fmaxf(d[3], 0.f));
    }

    if constexpr (STAGE == 4) {
        float d[4] = {0.f, 0.f, 0.f, 0.f};
        #pragma unroll 4
        for (int k = 0; k < 64; ++k) {
            float wc = Wc2[k * 64 + f];
            #pragma unroll
            for (int i = 0; i < 4; ++i)
                d[i] = fmaf(sC[(n0 + i) * SC + k], wc, d[i]);
        }
        float cg[4] = {ftanh(d[0]), ftanh(d[1]), ftanh(d[2]), ftanh(d[3])};
        float* hp = hT + ((size_t)b * 64 + f) * N_ + m0 + n0;
        float4 h4 = *(const float4*)hp;
        float4 z4 = *(const float4*)(zT + ((size_t)b * 64 + f) * N_ + m0 + n0);
        float hh[4] = {h4.x, h4.y, h4.z, h4.w};
        float zz[4] = {z4.x, z4.y, z4.z, z4.w};
        float hn[4];
        #pragma unroll
        for (int i = 0; i < 4; ++i) {
            float t1 = __fmul_rn(zz[i], hh[i]);
            float om = __fsub_rn(1.0f, zz[i]);
            float t2 = __fmul_rn(om, cg[i]);
            hn[i] = __fadd_rn(t1, t2);
        }
        *(float4*)hp = make_float4(hn[0], hn[1], hn[2], hn[3]);
        #pragma unroll
        for (int i = 0; i < 4; ++i)
            out[((size_t)bt * N_ + m0 + n0 + i) * 64 + f] = hn[i];
    }
    (void)s1;
}

// ================= launch =================

extern "C" void kernel_launch(void* const* d_in, const int* in_sizes, int n_in,
                              void* d_out, int out_size, void* d_ws, size_t ws_size,
                              hipStream_t stream) {
    (void)in_sizes; (void)n_in; (void)out_size; (void)ws_size;
    const float* x    = (const float*)d_in[0];
    const float* e    = (const float*)d_in[1];
    const float* fc_w = (const float*)d_in[2];
    const float* fc_b = (const float*)d_in[3];
    const float* Wz1  = (const float*)d_in[4];
    const float* Wz2  = (const float*)d_in[5];
    const float* Wr1  = (const float*)d_in[6];
    const float* Wr2  = (const float*)d_in[7];
    const float* Wc1  = (const float*)d_in[8];
    const float* Wc2  = (const float*)d_in[9];
    float* out = (float*)d_out;

    char* p = (char*)d_ws;
    auto alloc = [&](size_t bytes) { char* r = p; p += (bytes + 255) & ~(size_t)255; return r; };
    const size_t HSZ = (size_t)B_ * 64 * N_ * 4;
    float* xpT = (float*)alloc((size_t)B_ * T_ * 64 * N_ * 4);
    float* UX  = (float*)alloc((size_t)B_ * T_ * N_ * 64 * 4);
    float* hT  = (float*)alloc(HSZ);
    float* hzT = (float*)alloc(HSZ);
    float* hrT = (float*)alloc(HSZ);
    float* zT  = (float*)alloc(HSZ);
    float* rhT = (float*)alloc(HSZ);
    float* hcT = (float*)alloc(HSZ);

    xpT_kernel<<<dim3(8, B_ * T_), 256, 0, stream>>>(x, fc_w, fc_b, xpT);
    ux_kernel<<<dim3(64, B_ * T_), 64, 0, stream>>>(e, xpT, UX);
    hipMemsetAsync(hT, 0, HSZ, stream);

    dim3 grid(N_ / 8, B_);
    for (int t = 0; t < T_; ++t) {
        stage_kernel<1><<<grid, 128, 0, stream>>>(e, t, UX, Wz1, Wz2, Wr1, Wr2, Wc1, Wc2,
                                                  hT, hzT, hrT, zT, rhT, hcT, out);
        stage_kernel<2><<<grid, 128, 0, stream>>>(e, t, UX, Wz1, Wz2, Wr1, Wr2, Wc1, Wc2,
                                                  hT, hzT, hrT, zT, rhT, hcT, out);
        stage_kernel<3><<<grid, 128, 0, stream>>>(e, t, UX, Wz1, Wz2, Wr1, Wr2, Wc1, Wc2,
                                                  hT, hzT, hrT, zT, rhT, hcT, out);
        stage_kernel<4><<<grid, 128, 0, stream>>>(e, t, UX, Wz1, Wz2, Wr1, Wr2, Wc1, Wc2,
                                                  hT, hzT, hrT, zT, rhT, hcT, out);
    }
}

// Round 11
// 1733.763 us; speedup vs baseline: 1.8399x; 1.8399x over previous
//
#include <hip/hip_runtime.h>
#include <cstdint>
#include <cstddef>

#define B_ 4
#define T_ 24
#define N_ 512

// gate nonlinearities: evaluate in f64, round once to f32 (R4-proven numerics)
__device__ __forceinline__ float fsig(float x)  { return (float)(1.0 / (1.0 + exp(-(double)x))); }
__device__ __forceinline__ float ftanh(float x) { return (float)tanh((double)x); }

// 16-slot XOR swizzle for [F][64] LDS tiles (R7-proven)
__device__ __forceinline__ int swz16(int f) { return (((f & 15) ^ ((f >> 4) & 15)) << 2); }

// ================= PRECOMPUTE (parallel, recurrence-free) =================

// xp = relu(x @ fc_w + fc_b), stored feature-major xpT[bt][f][node]
__global__ __launch_bounds__(256) void xpT_kernel(const float* __restrict__ x,
                                                  const float* __restrict__ fc_w,
                                                  const float* __restrict__ fc_b,
                                                  float* __restrict__ xpT) {
    __shared__ __align__(16) float sX[64 * 68];
    __shared__ __align__(16) float sW[64 * 64];
    __shared__ float sB[64];
    const int bt = blockIdx.y;
    const int n0 = blockIdx.x * 64;
    const int tid = threadIdx.x;
    for (int i = tid * 4; i < 4096; i += 1024)
        *(float4*)&sW[i] = *(const float4*)&fc_w[i];
    if (tid < 64) sB[tid] = fc_b[tid];
    {
        int r = tid >> 2, kq = (tid & 3) * 16;
        const float* p = x + ((size_t)bt * N_ + n0 + r) * 64 + kq;
        #pragma unroll
        for (int j = 0; j < 4; ++j)
            *(float4*)&sX[r * 68 + kq + j * 4] = *(const float4*)(p + j * 4);
    }
    __syncthreads();
    const int f = tid & 63, ng = tid >> 6;
    float d[16];
    #pragma unroll
    for (int j = 0; j < 16; ++j) d[j] = 0.f;
    for (int k = 0; k < 64; ++k) {
        float w = sW[k * 64 + f];
        #pragma unroll
        for (int j = 0; j < 16; ++j)
            d[j] = fmaf(sX[(ng * 16 + j) * 68 + k], w, d[j]);
    }
    const float bias = sB[f];
    float* o = xpT + ((size_t)bt * 64 + f) * N_ + n0 + ng * 16;
    #pragma unroll
    for (int j = 0; j < 16; ++j)
        o[j] = fmaxf(__fadd_rn(d[j], bias), 0.f);
}

// UX[bt][node][64] = (A_bt @ xp_bt): 64x64 block tile, 4x4 register tiling
__global__ __launch_bounds__(256) void ux_kernel(const float* __restrict__ e,
                                                 const float* __restrict__ xpT,
                                                 float* __restrict__ UX) {
    __shared__ __align__(16) float sA[2][64 * 72];   // 36.9 KB (stride 72: 16B-aligned rows)
    __shared__ __align__(16) float sV[2][64 * 64];   // 32 KB, swizzled
    const int bt = blockIdx.y;
    const int m0 = blockIdx.x * 64;
    const int tid = threadIdx.x;
    const float* Ab = e + ((size_t)bt * N_ + m0) * N_;
    const float* s0 = xpT + (size_t)bt * 64 * N_;

    auto stageA = [&](float* dst, int kt) {
        const int r = tid >> 2, kq = (tid & 3) * 16;
        const float* src = Ab + (size_t)r * N_ + kt * 64 + kq;
        float* d = dst + r * 72 + kq;
        #pragma unroll
        for (int j = 0; j < 4; ++j)
            *(float4*)(d + j * 4) = *(const float4*)(src + j * 4);
    };
    auto stageV = [&](float* dst, int kt) {
        const int f = tid >> 2, q = tid & 3;
        const int sw = swz16(f);
        const float* src = s0 + (size_t)f * N_ + kt * 64;
        #pragma unroll
        for (int j = 0; j < 4; ++j) {
            int k = q * 16 + j * 4;
            *(float4*)&dst[f * 64 + (k ^ sw)] = *(const float4*)(src + k);
        }
    };

    stageA(sA[0], 0);
    stageV(sV[0], 0);
    __syncthreads();

    const int cg = tid & 15, rg = tid >> 4;
    const int c0 = cg * 4;
    float acc[4][4];
    #pragma unroll
    for (int i = 0; i < 4; ++i)
        #pragma unroll
        for (int j = 0; j < 4; ++j) acc[i][j] = 0.f;

    for (int kb = 0; kb < 8; ++kb) {
        if (kb < 7) { stageA(sA[(kb + 1) & 1], kb + 1); stageV(sV[(kb + 1) & 1], kb + 1); }
        const float* Ab_ = sA[kb & 1];
        const float* Vb_ = sV[kb & 1];
        #pragma unroll 4
        for (int kg = 0; kg < 16; ++kg) {
            const int k = kg * 4;
            float4 v[4], a[4];
            #pragma unroll
            for (int j = 0; j < 4; ++j)
                v[j] = *(const float4*)&Vb_[(c0 + j) * 64 + (k ^ swz16(c0 + j))];
            #pragma unroll
            for (int i = 0; i < 4; ++i)
                a[i] = *(const float4*)&Ab_[(rg * 4 + i) * 72 + k];
            #pragma unroll
            for (int i = 0; i < 4; ++i)
                #pragma unroll
                for (int j = 0; j < 4; ++j) {
                    acc[i][j] = fmaf(a[i].x, v[j].x, acc[i][j]);
                    acc[i][j] = fmaf(a[i].y, v[j].y, acc[i][j]);
                    acc[i][j] = fmaf(a[i].z, v[j].z, acc[i][j]);
                    acc[i][j] = fmaf(a[i].w, v[j].w, acc[i][j]);
                }
        }
        __syncthreads();
    }
    #pragma unroll
    for (int i = 0; i < 4; ++i)
        *(float4*)&UX[((size_t)bt * N_ + m0 + rg * 4 + i) * 64 + c0] =
            make_float4(acc[i][0], acc[i][1], acc[i][2], acc[i][3]);
}

// ================= STAGE KERNELS (multi-launch, BM=8, 256 blocks, 256 thr) =================
// S1: C = A@h;        hz = relu([UX|C]@Wz1); hr = relu([UX|C]@Wr1)
// S2: C = A@[hz|hr];  z = sig(C_z@Wz2) -> zT; rh = sig(C_r@Wr2)*h
// S3: C = A@rh;       hc = relu(UX@Wc1_top + C@Wc1_bot)
// S4: C = A@hc;       c = tanh(C@Wc2); hn = z*h + (1-z)*c -> hT, out
template <int STAGE>
__global__ __launch_bounds__(256) void stage9_kernel(
    const float* __restrict__ e, int t,
    const float* __restrict__ UX,
    const float* __restrict__ Wz1, const float* __restrict__ Wz2,
    const float* __restrict__ Wr1, const float* __restrict__ Wr2,
    const float* __restrict__ Wc1, const float* __restrict__ Wc2,
    float* __restrict__ hT, float* __restrict__ hzT, float* __restrict__ hrT,
    float* __restrict__ zT, float* __restrict__ rhT, float* __restrict__ hcT,
    float* __restrict__ out)
{
    constexpr int F = (STAGE == 2) ? 128 : 64;
    constexpr int SC = F + 4;
    __shared__ __align__(16) float sA[8 * 512];          // 16 KB
    __shared__ __align__(16) float sV[2 * F * 64];       // 64 KB (F=128) / 32 KB
    __shared__ __align__(16) float sC[8 * SC];
    __shared__ __align__(16) float sUX[8 * 68];

    const int b = blockIdx.y;
    const int m0 = blockIdx.x * 8;
    const int tid = threadIdx.x;
    const int bt = b * T_ + t;

    const float* Ab = e + ((size_t)bt * N_ + m0) * N_;

    const float* s0;
    const float* s1 = nullptr;
    if (STAGE == 1)      { s0 = hT  + (size_t)b * 64 * N_; }
    else if (STAGE == 2) { s0 = hzT + (size_t)b * 64 * N_; s1 = hrT + (size_t)b * 64 * N_; }
    else if (STAGE == 3) { s0 = rhT + (size_t)b * 64 * N_; }
    else                 { s0 = hcT + (size_t)b * 64 * N_; }

    {   // stage A rows [8][512]
        const int r = tid >> 5, seg = (tid & 31) * 16;
        const float* src = Ab + (size_t)r * N_ + seg;
        float* dst = sA + r * 512 + seg;
        #pragma unroll
        for (int j = 0; j < 4; ++j)
            *(float4*)(dst + j * 4) = *(const float4*)(src + j * 4);
    }
    if constexpr (STAGE == 1 || STAGE == 3) {
        if (tid < 128) {    // stage UX tile [8][64]
            const int n = tid >> 4, q = (tid & 15) * 4;
            *(float4*)&sUX[n * 68 + q] =
                *(const float4*)&UX[((size_t)bt * N_ + m0 + n) * 64 + q];
        }
    }

    auto stageV = [&](float* dst, int kt) {
        if constexpr (F == 128) {
            const int f = tid >> 1, h = tid & 1;
            const float* src = ((f < 64) ? (s0 + (size_t)f * N_)
                                         : (s1 + (size_t)(f - 64) * N_)) + kt * 64 + h * 32;
            const int sw = swz16(f);
            #pragma unroll
            for (int j = 0; j < 8; ++j)
                *(float4*)&dst[f * 64 + ((h * 32 + j * 4) ^ sw)] = *(const float4*)(src + j * 4);
        } else {
            const int f = tid >> 2, q = tid & 3;
            const float* src = s0 + (size_t)f * N_ + kt * 64 + q * 16;
            const int sw = swz16(f);
            #pragma unroll
            for (int j = 0; j < 4; ++j)
                *(float4*)&dst[f * 64 + ((q * 16 + j * 4) ^ sw)] = *(const float4*)(src + j * 4);
        }
    };

    // ---- conv: C = A @ V, double-buffered, strict ascending-k fmaf chains (R9-proven) ----
    constexpr int RPT = (F == 128) ? 4 : 2;
    const int c = tid & (F - 1);
    const int rg = (F == 128) ? (tid >> 7) : (tid >> 6);
    const int swc = swz16(c);
    float acc[RPT];
    #pragma unroll
    for (int i = 0; i < RPT; ++i) acc[i] = 0.f;

    stageV(sV, 0);
    __syncthreads();
    for (int kb = 0; kb < 8; ++kb) {
        if (kb < 7) stageV(sV + ((kb + 1) & 1) * (F * 64), kb + 1);
        const float* buf = sV + (kb & 1) * (F * 64);
        #pragma unroll 4
        for (int kg = 0; kg < 16; ++kg) {
            const int k = kg * 4;
            float4 v = *(const float4*)&buf[c * 64 + (k ^ swc)];
            #pragma unroll
            for (int i = 0; i < RPT; ++i) {
                float4 x = *(const float4*)&sA[(rg * RPT + i) * 512 + kb * 64 + k];
                acc[i] = fmaf(x.x, v.x, acc[i]);
                acc[i] = fmaf(x.y, v.y, acc[i]);
                acc[i] = fmaf(x.z, v.z, acc[i]);
                acc[i] = fmaf(x.w, v.w, acc[i]);
            }
        }
        __syncthreads();
    }
    #pragma unroll
    for (int i = 0; i < RPT; ++i)
        sC[(rg * RPT + i) * SC + c] = acc[i];
    __syncthreads();

    // ---- epilogues: b128 row reads (4x fewer LDS instrs), chains bit-identical ----
    if constexpr (STAGE == 1) {
        const int sel = tid >> 7, f = tid & 63, ng = (tid >> 6) & 1, n0 = ng * 4;
        const float* W = sel ? Wr1 : Wz1;
        float d[4] = {0.f, 0.f, 0.f, 0.f};
        #pragma unroll 4
        for (int kq = 0; kq < 16; ++kq) {   // U part: k = 0..63
            float4 u0 = *(const float4*)&sUX[(n0 + 0) * 68 + kq * 4];
            float4 u1 = *(const float4*)&sUX[(n0 + 1) * 68 + kq * 4];
            float4 u2 = *(const float4*)&sUX[(n0 + 2) * 68 + kq * 4];
            float4 u3 = *(const float4*)&sUX[(n0 + 3) * 68 + kq * 4];
            const float* Wp = W + (kq * 4) * 64 + f;
            float w0 = Wp[0], w1 = Wp[64], w2 = Wp[128], w3 = Wp[192];
            d[0]=fmaf(u0.x,w0,d[0]); d[1]=fmaf(u1.x,w0,d[1]); d[2]=fmaf(u2.x,w0,d[2]); d[3]=fmaf(u3.x,w0,d[3]);
            d[0]=fmaf(u0.y,w1,d[0]); d[1]=fmaf(u1.y,w1,d[1]); d[2]=fmaf(u2.y,w1,d[2]); d[3]=fmaf(u3.y,w1,d[3]);
            d[0]=fmaf(u0.z,w2,d[0]); d[1]=fmaf(u1.z,w2,d[1]); d[2]=fmaf(u2.z,w2,d[2]); d[3]=fmaf(u3.z,w2,d[3]);
            d[0]=fmaf(u0.w,w3,d[0]); d[1]=fmaf(u1.w,w3,d[1]); d[2]=fmaf(u2.w,w3,d[2]); d[3]=fmaf(u3.w,w3,d[3]);
        }
        #pragma unroll 4
        for (int kq = 0; kq < 16; ++kq) {   // C part: W rows 64..127
            float4 c0_ = *(const float4*)&sC[(n0 + 0) * SC + kq * 4];
            float4 c1_ = *(const float4*)&sC[(n0 + 1) * SC + kq * 4];
            float4 c2_ = *(const float4*)&sC[(n0 + 2) * SC + kq * 4];
            float4 c3_ = *(const float4*)&sC[(n0 + 3) * SC + kq * 4];
            const float* Wp = W + (64 + kq * 4) * 64 + f;
            float w0 = Wp[0], w1 = Wp[64], w2 = Wp[128], w3 = Wp[192];
            d[0]=fmaf(c0_.x,w0,d[0]); d[1]=fmaf(c1_.x,w0,d[1]); d[2]=fmaf(c2_.x,w0,d[2]); d[3]=fmaf(c3_.x,w0,d[3]);
            d[0]=fmaf(c0_.y,w1,d[0]); d[1]=fmaf(c1_.y,w1,d[1]); d[2]=fmaf(c2_.y,w1,d[2]); d[3]=fmaf(c3_.y,w1,d[3]);
            d[0]=fmaf(c0_.z,w2,d[0]); d[1]=fmaf(c1_.z,w2,d[1]); d[2]=fmaf(c2_.z,w2,d[2]); d[3]=fmaf(c3_.z,w2,d[3]);
            d[0]=fmaf(c0_.w,w3,d[0]); d[1]=fmaf(c1_.w,w3,d[1]); d[2]=fmaf(c2_.w,w3,d[2]); d[3]=fmaf(c3_.w,w3,d[3]);
        }
        float* dstT = (sel ? hrT : hzT) + (size_t)b * 64 * N_;
        *(float4*)(dstT + (size_t)f * N_ + m0 + n0) =
            make_float4(fmaxf(d[0], 0.f), fmaxf(d[1], 0.f), fmaxf(d[2], 0.f), fmaxf(d[3], 0.f));
    }

    if constexpr (STAGE == 2) {
        const int sel = tid >> 7, f = tid & 63, ng = (tid >> 6) & 1, n0 = ng * 4;
        const float* W = sel ? Wr2 : Wz2;
        const int off = sel * 64;
        float d[4] = {0.f, 0.f, 0.f, 0.f};
        #pragma unroll 4
        for (int kq = 0; kq < 16; ++kq) {
            float4 c0_ = *(const float4*)&sC[(n0 + 0) * SC + off + kq * 4];
            float4 c1_ = *(const float4*)&sC[(n0 + 1) * SC + off + kq * 4];
            float4 c2_ = *(const float4*)&sC[(n0 + 2) * SC + off + kq * 4];
            float4 c3_ = *(const float4*)&sC[(n0 + 3) * SC + off + kq * 4];
            const float* Wp = W + (kq * 4) * 64 + f;
            float w0 = Wp[0], w1 = Wp[64], w2 = Wp[128], w3 = Wp[192];
            d[0]=fmaf(c0_.x,w0,d[0]); d[1]=fmaf(c1_.x,w0,d[1]); d[2]=fmaf(c2_.x,w0,d[2]); d[3]=fmaf(c3_.x,w0,d[3]);
            d[0]=fmaf(c0_.y,w1,d[0]); d[1]=fmaf(c1_.y,w1,d[1]); d[2]=fmaf(c2_.y,w1,d[2]); d[3]=fmaf(c3_.y,w1,d[3]);
            d[0]=fmaf(c0_.z,w2,d[0]); d[1]=fmaf(c1_.z,w2,d[1]); d[2]=fmaf(c2_.z,w2,d[2]); d[3]=fmaf(c3_.z,w2,d[3]);
            d[0]=fmaf(c0_.w,w3,d[0]); d[1]=fmaf(c1_.w,w3,d[1]); d[2]=fmaf(c2_.w,w3,d[2]); d[3]=fmaf(c3_.w,w3,d[3]);
        }
        if (!sel) {
            *(float4*)(zT + ((size_t)b * 64 + f) * N_ + m0 + n0) =
                make_float4(fsig(d[0]), fsig(d[1]), fsig(d[2]), fsig(d[3]));
        } else {
            float4 h4 = *(const float4*)(hT + ((size_t)b * 64 + f) * N_ + m0 + n0);
            *(float4*)(rhT + ((size_t)b * 64 + f) * N_ + m0 + n0) =
                make_float4(__fmul_rn(fsig(d[0]), h4.x), __fmul_rn(fsig(d[1]), h4.y),
                            __fmul_rn(fsig(d[2]), h4.z), __fmul_rn(fsig(d[3]), h4.w));
        }
    }

    if constexpr (STAGE == 3) {
        const int f = tid & 63, ng = tid >> 6, n0 = ng * 2;
        float d[2] = {0.f, 0.f};
        #pragma unroll 4
        for (int kq = 0; kq < 16; ++kq) {   // U part
            float4 u0 = *(const float4*)&sUX[(n0 + 0) * 68 + kq * 4];
            float4 u1 = *(const float4*)&sUX[(n0 + 1) * 68 + kq * 4];
            const float* Wp = Wc1 + (kq * 4) * 64 + f;
            float w0 = Wp[0], w1 = Wp[64], w2 = Wp[128], w3 = Wp[192];
            d[0]=fmaf(u0.x,w0,d[0]); d[1]=fmaf(u1.x,w0,d[1]);
            d[0]=fmaf(u0.y,w1,d[0]); d[1]=fmaf(u1.y,w1,d[1]);
            d[0]=fmaf(u0.z,w2,d[0]); d[1]=fmaf(u1.z,w2,d[1]);
            d[0]=fmaf(u0.w,w3,d[0]); d[1]=fmaf(u1.w,w3,d[1]);
        }
        #pragma unroll 4
        for (int kq = 0; kq < 16; ++kq) {   // C part, W rows 64..127
            float4 c0_ = *(const float4*)&sC[(n0 + 0) * SC + kq * 4];
            float4 c1_ = *(const float4*)&sC[(n0 + 1) * SC + kq * 4];
            const float* Wp = Wc1 + (64 + kq * 4) * 64 + f;
            float w0 = Wp[0], w1 = Wp[64], w2 = Wp[128], w3 = Wp[192];
            d[0]=fmaf(c0_.x,w0,d[0]); d[1]=fmaf(c1_.x,w0,d[1]);
            d[0]=fmaf(c0_.y,w1,d[0]); d[1]=fmaf(c1_.y,w1,d[1]);
            d[0]=fmaf(c0_.z,w2,d[0]); d[1]=fmaf(c1_.z,w2,d[1]);
            d[0]=fmaf(c0_.w,w3,d[0]); d[1]=fmaf(c1_.w,w3,d[1]);
        }
        *(float2*)(hcT + ((size_t)b * 64 + f) * N_ + m0 + n0) =
            make_float2(fmaxf(d[0], 0.f), fmaxf(d[1], 0.f));
    }

    if constexpr (STAGE == 4) {
        const int f = tid & 63, ng = tid >> 6, n0 = ng * 2;
        float d[2] = {0.f, 0.f};
        #pragma unroll 4
        for (int kq = 0; kq < 16; ++kq) {
            float4 c0_ = *(const float4*)&sC[(n0 + 0) * SC + kq * 4];
            float4 c1_ = *(const float4*)&sC[(n0 + 1) * SC + kq * 4];
            const float* Wp = Wc2 + (kq * 4) * 64 + f;
            float w0 = Wp[0], w1 = Wp[64], w2 = Wp[128], w3 = Wp[192];
            d[0]=fmaf(c0_.x,w0,d[0]); d[1]=fmaf(c1_.x,w0,d[1]);
            d[0]=fmaf(c0_.y,w1,d[0]); d[1]=fmaf(c1_.y,w1,d[1]);
            d[0]=fmaf(c0_.z,w2,d[0]); d[1]=fmaf(c1_.z,w2,d[1]);
            d[0]=fmaf(c0_.w,w3,d[0]); d[1]=fmaf(c1_.w,w3,d[1]);
        }
        float c0 = ftanh(d[0]), c1 = ftanh(d[1]);
        float* hp = hT + ((size_t)b * 64 + f) * N_ + m0 + n0;
        float2 h2 = *(const float2*)hp;
        float2 z2 = *(const float2*)(zT + ((size_t)b * 64 + f) * N_ + m0 + n0);
        float hn0 = __fadd_rn(__fmul_rn(z2.x, h2.x), __fmul_rn(__fsub_rn(1.f, z2.x), c0));
        float hn1 = __fadd_rn(__fmul_rn(z2.y, h2.y), __fmul_rn(__fsub_rn(1.f, z2.y), c1));
        *(float2*)hp = make_float2(hn0, hn1);
        out[((size_t)bt * N_ + m0 + n0) * 64 + f] = hn0;
        out[((size_t)bt * N_ + m0 + n0 + 1) * 64 + f] = hn1;
    }
    (void)s1;
}

// ================= launch =================

extern "C" void kernel_launch(void* const* d_in, const int* in_sizes, int n_in,
                              void* d_out, int out_size, void* d_ws, size_t ws_size,
                              hipStream_t stream) {
    (void)in_sizes; (void)n_in; (void)out_size; (void)ws_size;
    const float* x    = (const float*)d_in[0];
    const float* e    = (const float*)d_in[1];
    const float* fc_w = (const float*)d_in[2];
    const float* fc_b = (const float*)d_in[3];
    const float* Wz1  = (const float*)d_in[4];
    const float* Wz2  = (const float*)d_in[5];
    const float* Wr1  = (const float*)d_in[6];
    const float* Wr2  = (const float*)d_in[7];
    const float* Wc1  = (const float*)d_in[8];
    const float* Wc2  = (const float*)d_in[9];
    float* out = (float*)d_out;

    char* p = (char*)d_ws;
    auto alloc = [&](size_t bytes) { char* r = p; p += (bytes + 255) & ~(size_t)255; return r; };
    const size_t HSZ = (size_t)B_ * 64 * N_ * 4;
    float* xpT = (float*)alloc((size_t)B_ * T_ * 64 * N_ * 4);
    float* UX  = (float*)alloc((size_t)B_ * T_ * N_ * 64 * 4);
    float* hT  = (float*)alloc(HSZ);
    float* hzT = (float*)alloc(HSZ);
    float* hrT = (float*)alloc(HSZ);
    float* zT  = (float*)alloc(HSZ);
    float* rhT = (float*)alloc(HSZ);
    float* hcT = (float*)alloc(HSZ);

    xpT_kernel<<<dim3(8, B_ * T_), 256, 0, stream>>>(x, fc_w, fc_b, xpT);
    ux_kernel<<<dim3(8, B_ * T_), 256, 0, stream>>>(e, xpT, UX);
    hipMemsetAsync(hT, 0, HSZ, stream);

    dim3 grid(N_ / 8, B_);
    for (int t = 0; t < T_; ++t) {
        stage9_kernel<1><<<grid, 256, 0, stream>>>(e, t, UX, Wz1, Wz2, Wr1, Wr2, Wc1, Wc2,
                                                   hT, hzT, hrT, zT, rhT, hcT, out);
        stage9_kernel<2><<<grid, 256, 0, stream>>>(e, t, UX, Wz1, Wz2, Wr1, Wr2, Wc1, Wc2,
                                                   hT, hzT, hrT, zT, rhT, hcT, out);
        stage9_kernel<3><<<grid, 256, 0, stream>>>(e, t, UX, Wz1, Wz2, Wr1, Wr2, Wc1, Wc2,
                                                   hT, hzT, hrT, zT, rhT, hcT, out);
        stage9_kernel<4><<<grid, 256, 0, stream>>>(e, t, UX, Wz1, Wz2, Wr1, Wr2, Wc1, Wc2,
                                                   hT, hzT, hrT, zT, rhT, hcT, out);
    }
}